// Round 11
// baseline (782.879 us; speedup 1.0000x reference)
//
#include <hip/hip_runtime.h>
#include <math.h>

#define BATCH 32
#define TSEQ  4096
#define HD    128
#define NST   128
#define BT    (BATCH*TSEQ)     // 131072
#define LC    64               // scan chunk length
#define NCHK  (TSEQ/LC)        // 64 chunks

typedef unsigned short bf16;
typedef __attribute__((ext_vector_type(8))) short bf16x8;   // 8 bf16 = 4 VGPRs (MFMA A/B frag)
typedef __attribute__((ext_vector_type(4))) float f32x4;
typedef __attribute__((ext_vector_type(16))) float f32x16;  // 32x32 MFMA C/D frag

__device__ inline float bf2f(bf16 s) {
    union { unsigned int u; float f; } v; v.u = ((unsigned int)s) << 16; return v.f;
}
__device__ inline bf16 f2bf(float f) {
    union { float f; unsigned int u; } v; v.f = f;
    unsigned int u = v.u;
    unsigned int r = (u + 0x7fffu + ((u >> 16) & 1u)) >> 16;
    return (bf16)r;
}
// pack two f32 -> bf16 pair (round-half-up) in ~3 VALU via v_perm
__device__ inline unsigned int pkpair(float lo, float hi) {
    union { float f; unsigned int u; } a, b;
    a.f = lo; b.f = hi;
    return __builtin_amdgcn_perm(b.u + 0x8000u, a.u + 0x8000u, 0x07060302u);
}
__device__ inline bf16x8 pack8f(float4 f0, float4 f1) {
    union { bf16x8 v; unsigned int u[4]; } t;
    t.u[0] = pkpair(f0.x, f0.y);
    t.u[1] = pkpair(f0.z, f0.w);
    t.u[2] = pkpair(f1.x, f1.y);
    t.u[3] = pkpair(f1.z, f1.w);
    return t.v;
}
__device__ inline float2 cmul2(float2 a, float2 b) {
    return make_float2(a.x*b.x - a.y*b.y, a.x*b.y + a.y*b.x);
}
// tanh-form gelu: max |diff vs exact erf-gelu| ~1e-3, under bf16 noise here
__device__ inline float gelu_f(float x) {
    float u = x*(0.7978845608f + 0.0356774081f*x*x);
    return __fdividef(x, 1.f + __expf(-2.f*u));
}
__device__ inline float2 upk(unsigned int w) {     // bf16 pair -> fp32 pair
    union { unsigned int u; float f; } a, b;
    a.u = w << 16; b.u = w & 0xffff0000u;
    return make_float2(a.f, b.f);
}
__device__ inline unsigned int pk(float2 x) { return pkpair(x.x, x.y); }

// ---------------- S5 param prep: g-folded W'bu, S/bias corrections, Wc, gd/bd, coefs ----
__global__ void prep_s5(const float* __restrict__ Lam_re, const float* __restrict__ Lam_im,
                        const float* __restrict__ B_re,  const float* __restrict__ B_im,
                        const float* __restrict__ C_re,  const float* __restrict__ C_im,
                        const float* __restrict__ log_step,
                        const float* __restrict__ ln1_g, const float* __restrict__ ln1_b,
                        const float* __restrict__ D_skip,
                        bf16* __restrict__ Wbu_bf,  // [2][256][128], row 2n=Re 2n+1=Im, g-folded
                        bf16* __restrict__ Wc_bf,   // [2][128][256], col 2n=2Cre 2n+1=-2Cim
                        float* __restrict__ Sb, float* __restrict__ biasb,   // [2][256]
                        float* __restrict__ gd, float* __restrict__ bd,      // [2][128]
                        float4* __restrict__ coefs)
{
    int i = blockIdx.x, n = threadIdx.x;
    int in = i*NST + n;
    float lr = Lam_re[in], li = Lam_im[in];
    float dt = expf(log_step[in]);
    float ea = expf(lr*dt);
    float ar = ea*cosf(li*dt), ai = ea*sinf(li*dt);
    float xx = ar - 1.f, yy = ai;
    float den = lr*lr + li*li;
    float sr = (xx*lr + yy*li)/den;
    float si = (yy*lr - xx*li)/den;
    float2 p = make_float2(ar, ai);
    #pragma unroll
    for (int q = 0; q < 6; ++q) p = cmul2(p, p);   // a^64
    coefs[in] = make_float4(ar, ai, p.x, p.y);

    const float* g  = ln1_g + i*HD;
    const float* bb = ln1_b + i*HD;
    const float* br = B_re + (size_t)in*HD;
    const float* bi = B_im + (size_t)in*HD;
    bf16* wb = Wbu_bf + (size_t)i*256*128;
    float s_re = 0.f, s_im = 0.f, bc_re = 0.f, bc_im = 0.f;
    for (int h = 0; h < HD; ++h) {
        float wre = sr*br[h] - si*bi[h];
        float wim = sr*bi[h] + si*br[h];
        bf16 wrb = f2bf(g[h]*wre), wib = f2bf(g[h]*wim);
        wb[(2*n)*128 + h]   = wrb;
        wb[(2*n+1)*128 + h] = wib;
        s_re += bf2f(wrb); s_im += bf2f(wib);
        bc_re += bb[h]*wre; bc_im += bb[h]*wim;
    }
    Sb[i*256 + 2*n] = s_re;     Sb[i*256 + 2*n+1] = s_im;
    biasb[i*256 + 2*n] = bc_re; biasb[i*256 + 2*n+1] = bc_im;

    const float* cr = C_re + (size_t)i*HD*NST;
    const float* ci = C_im + (size_t)i*HD*NST;
    bf16* wc = Wc_bf + (size_t)i*128*256;
    for (int h = 0; h < HD; ++h) {
        wc[h*256 + 2*n]   = f2bf( 2.f * cr[h*NST + n]);
        wc[h*256 + 2*n+1] = f2bf(-2.f * ci[h*NST + n]);
    }
    gd[i*HD + n] = g[n]*D_skip[i*HD + n];
    bd[i*HD + n] = bb[n]*D_skip[i*HD + n];
}

// W1 -> g2-folded bf16 [f][h] + S1/bias1' (bias1' includes b1)
__global__ void prep_w1(const float* __restrict__ W1, const float* __restrict__ b1,
                        const float* __restrict__ ln2_g, const float* __restrict__ ln2_b,
                        bf16* __restrict__ W1_bf, float* __restrict__ S1,
                        float* __restrict__ bias1p)
{
    int i = blockIdx.x, f = threadIdx.x;       // f in [0,256)
    const float* g  = ln2_g + i*HD;
    const float* bb = ln2_b + i*HD;
    bf16* w = W1_bf + (size_t)i*256*128;
    float S = 0.f, bi_ = b1[i*256 + f];
    for (int h = 0; h < HD; ++h) {
        float wv = W1[(size_t)i*32768 + h*256 + f];
        bf16 wbv = f2bf(g[h]*wv);
        w[f*128 + h] = wbv;
        S += bf2f(wbv);
        bi_ += bb[h]*wv;
    }
    S1[i*256 + f] = S;
    bias1p[i*256 + f] = bi_;
}

// W2 -> plain bf16 transposed [h][f]
__global__ void prep_w2(const float* __restrict__ W2, bf16* __restrict__ W2_bf)
{
    int i = blockIdx.x, h = threadIdx.x;       // h in [0,128)
    bf16* w = W2_bf + (size_t)i*128*256;
    for (int f = 0; f < 256; ++f)
        w[h*256 + f] = f2bf(W2[(size_t)i*32768 + f*128 + h]);
}

// conv weights [c][ic][tap] -> bf16 [c][tap*128+ic]
__global__ void prep_wB(const float* __restrict__ w1, const float* __restrict__ w2,
                        bf16* __restrict__ wB1, bf16* __restrict__ wB2)
{
    int idx = blockIdx.x*256 + threadIdx.x;
    if (idx >= 163840) return;
    const float* w = (idx < 81920) ? w1 : w2;
    bf16* wb       = (idx < 81920) ? wB1 : wB2;
    int r   = idx % 81920;
    int c   = r / 640;
    int tap = (r % 640) / 128;
    int ic  = r % 128;
    wb[r] = f2bf(w[(c*128 + ic)*5 + tap]);
}

// ---------------- fused LN + GEMM (K=128, N=256), 32x32x16 MFMA, no LDS --------------
// Weights as A-operand (L2-hot direct loads), activations as B-operand.
// D: col=lane&31 = t, row=(reg&3)+8*(reg>>2)+4*(lane>>5) = n within 32-tile.
// UD=1: stores per-row (mu,rs); no activation (Bu). UD=0: gelu (h).
template<int UD, typename TA>
__global__ __launch_bounds__(256, 4) void lngemm(
    const TA* __restrict__ A,          // [BT,128] fp32 or bf16
    const bf16* __restrict__ Bt,       // [256][128] g-folded
    const float* __restrict__ Svec, const float* __restrict__ bvec,  // [256]
    bf16* __restrict__ outB,           // [BT,256]
    float2* __restrict__ munrs)        // [BT], UD=1 only
{
    int tid = threadIdx.x;
    int wave = tid >> 6, lane = tid & 63;
    int tl = lane & 31;                // t within 32-row strip
    int kh = lane >> 5;                // k-half (0/1): lane covers k = kt*16 + kh*8 + i
    int s = blockIdx.x*4 + wave;       // strip [0, 4096)
    size_t row = (size_t)s*32 + tl;

    // A-load (act): 8 frags, streaming LN stats (lane covers 64 of 128 k)
    bf16x8 af[8];
    float sm = 0.f, sq = 0.f;
    if constexpr (sizeof(TA) == 2) {
        const bf16* ar = (const bf16*)A + row*128 + kh*8;
        #pragma unroll
        for (int kt = 0; kt < 8; ++kt) {
            af[kt] = *(const bf16x8*)(ar + kt*16);
            union { bf16x8 v; unsigned int u[4]; } aa; aa.v = af[kt];
            #pragma unroll
            for (int jp = 0; jp < 4; ++jp) {
                float2 vv = upk(aa.u[jp]);
                sm += vv.x + vv.y;
                sq += vv.x*vv.x + vv.y*vv.y;
            }
        }
    } else {
        const float* ar = (const float*)A + row*128 + kh*8;
        #pragma unroll
        for (int kt = 0; kt < 8; ++kt) {
            float4 f0 = *(const float4*)(ar + kt*16);
            float4 f1 = *(const float4*)(ar + kt*16 + 4);
            sm += f0.x + f0.y + f0.z + f0.w + f1.x + f1.y + f1.z + f1.w;
            sq += f0.x*f0.x + f0.y*f0.y + f0.z*f0.z + f0.w*f0.w
                + f1.x*f1.x + f1.y*f1.y + f1.z*f1.z + f1.w*f1.w;
            af[kt] = pack8f(f0, f1);
        }
    }
    sm += __shfl_xor(sm, 32);          // combine the two k-halves of this row
    sq += __shfl_xor(sq, 32);
    float mu = sm * (1.f/128.f);
    float rs = rsqrtf(sq*(1.f/128.f) - mu*mu + 1e-5f);
    float mr = mu*rs;

    if constexpr (UD) {
        if (kh == 0) munrs[row] = make_float2(mu, rs);
    }

    #pragma unroll
    for (int nt = 0; nt < 8; ++nt) {
        const bf16* wr = Bt + (size_t)(nt*32 + tl)*128 + kh*8;   // weight row m
        f32x16 acc = {};
        #pragma unroll
        for (int kt = 0; kt < 8; ++kt)
            acc = __builtin_amdgcn_mfma_f32_32x32x16_bf16(
                      *(const bf16x8*)(wr + kt*16), af[kt], acc, 0, 0, 0);
        #pragma unroll
        for (int rg = 0; rg < 4; ++rg) {
            int n0 = nt*32 + rg*8 + kh*4;
            float4 S4 = *(const float4*)&Svec[n0];
            float4 b4 = *(const float4*)&bvec[n0];
            float4 o;
            o.x = rs*acc[rg*4+0] - mr*S4.x + b4.x;
            o.y = rs*acc[rg*4+1] - mr*S4.y + b4.y;
            o.z = rs*acc[rg*4+2] - mr*S4.z + b4.z;
            o.w = rs*acc[rg*4+3] - mr*S4.w + b4.w;
            if constexpr (!UD) {
                o.x = gelu_f(o.x); o.y = gelu_f(o.y);
                o.z = gelu_f(o.z); o.w = gelu_f(o.w);
            }
            uint2 pu = make_uint2(pkpair(o.x, o.y), pkpair(o.z, o.w));
            *(uint2*)(outB + row*256 + n0) = pu;
        }
    }
}

// ---------------- GEMM K=256 N=128 (bf16 A), 32x32x16 MFMA, no LDS -------------------
// EPI=2: out = acc + bias + resid.  EPI=3: out = resid + acc + (resid-mu)*rs*gd + bd.
template<int EPI, typename TR>
__global__ __launch_bounds__(256, 4) void gemm2(
    const bf16* __restrict__ A,        // [BT,256]
    const bf16* __restrict__ Bt,       // [128][256]
    bf16* out,                         // [BT,128] (may alias resid, same-elem r-then-w)
    const float* __restrict__ bias,    // EPI=2
    const TR* resid,                   // [BT,128]
    const float2* __restrict__ munrs,  // EPI=3
    const float* __restrict__ gdp, const float* __restrict__ bdp)   // EPI=3
{
    int tid = threadIdx.x;
    int wave = tid >> 6, lane = tid & 63;
    int tl = lane & 31;
    int kh = lane >> 5;
    int s = blockIdx.x*4 + wave;
    size_t row = (size_t)s*32 + tl;

    float mu = 0.f, rs = 0.f;
    if constexpr (EPI == 3) { float2 m2 = munrs[row]; mu = m2.x; rs = m2.y; }

    bf16x8 af[16];                     // K=256: lane covers kt*16 + kh*8 + i, kt=0..15
    const bf16* ar = A + row*256 + kh*8;
    #pragma unroll
    for (int kt = 0; kt < 16; ++kt)
        af[kt] = *(const bf16x8*)(ar + kt*16);

    #pragma unroll
    for (int nt = 0; nt < 4; ++nt) {
        const bf16* wr = Bt + (size_t)(nt*32 + tl)*256 + kh*8;
        f32x16 acc = {};
        #pragma unroll
        for (int kt = 0; kt < 16; ++kt)
            acc = __builtin_amdgcn_mfma_f32_32x32x16_bf16(
                      *(const bf16x8*)(wr + kt*16), af[kt], acc, 0, 0, 0);
        #pragma unroll
        for (int rg = 0; rg < 4; ++rg) {
            int n0 = nt*32 + rg*8 + kh*4;
            size_t oidx = row*128 + n0;
            float4 rv;
            if constexpr (sizeof(TR) == 2) {
                ushort4 u4 = *(const ushort4*)((const bf16*)resid + oidx);
                rv = make_float4(bf2f(u4.x), bf2f(u4.y), bf2f(u4.z), bf2f(u4.w));
            } else {
                rv = *(const float4*)((const float*)resid + oidx);
            }
            float4 o;
            if constexpr (EPI == 2) {
                float4 bv = *(const float4*)&bias[n0];
                o.x = acc[rg*4+0] + bv.x + rv.x; o.y = acc[rg*4+1] + bv.y + rv.y;
                o.z = acc[rg*4+2] + bv.z + rv.z; o.w = acc[rg*4+3] + bv.w + rv.w;
            } else {
                float4 g4 = *(const float4*)&gdp[n0];
                float4 b4 = *(const float4*)&bdp[n0];
                o.x = rv.x + acc[rg*4+0] + (rv.x - mu)*rs*g4.x + b4.x;
                o.y = rv.y + acc[rg*4+1] + (rv.y - mu)*rs*g4.y + b4.y;
                o.z = rv.z + acc[rg*4+2] + (rv.z - mu)*rs*g4.z + b4.z;
                o.w = rv.w + acc[rg*4+3] + (rv.w - mu)*rs*g4.w + b4.w;
            }
            uint2 pu = make_uint2(pkpair(o.x, o.y), pkpair(o.z, o.w));
            *(uint2*)(out + oidx) = pu;
        }
    }
}

// ---------------- chunked scan on bf16-pair xs: x_t = a*x_{t-1} + Bu_t ---------------
__global__ __launch_bounds__(256) void scan_local(unsigned int* __restrict__ xs,
                                                  const float4* __restrict__ coefs,
                                                  float2* __restrict__ carry)
{
    int flat = blockIdx.x*256 + threadIdx.x;  // 2^18
    int n = flat & 127;
    int b = (flat >> 7) & 31;
    int c = flat >> 12;
    float4 cf = coefs[n];
    float2 a = make_float2(cf.x, cf.y);
    unsigned int* base = xs + ((size_t)(b*TSEQ + c*LC))*NST + n;
    float2 x = make_float2(0.f, 0.f);
    for (int j = 0; j < LC; ++j) {
        float2 v = upk(base[(size_t)j*NST]);
        x = make_float2(a.x*x.x - a.y*x.y + v.x, a.x*x.y + a.y*x.x + v.y);
        base[(size_t)j*NST] = pk(x);
    }
    carry[c*(BATCH*NST) + b*NST + n] = x;
}

__global__ void scan_carry(float2* __restrict__ carry, const float4* __restrict__ coefs)
{
    int flat = blockIdx.x*256 + threadIdx.x;  // 4096 = B*N
    int n = flat & 127;
    float4 cf = coefs[n];
    float2 aL = make_float2(cf.z, cf.w);
    float2 x = make_float2(0.f, 0.f);
    for (int c = 0; c < NCHK; ++c) {
        float2* p = carry + c*(BATCH*NST) + flat;
        float2 v = *p;
        *p = x;                                // exclusive prefix
        x = make_float2(aL.x*x.x - aL.y*x.y + v.x, aL.x*x.y + aL.y*x.x + v.y);
    }
}

__global__ __launch_bounds__(256) void scan_fix(unsigned int* __restrict__ xs,
                                                const float4* __restrict__ coefs,
                                                const float2* __restrict__ carry)
{
    int flat = blockIdx.x*256 + threadIdx.x;
    int n = flat & 127;
    int b = (flat >> 7) & 31;
    int c = flat >> 12;
    if (c == 0) return;
    float2 cin = carry[c*(BATCH*NST) + b*NST + n];
    float4 cf = coefs[n];
    float2 a = make_float2(cf.x, cf.y);
    unsigned int* base = xs + ((size_t)(b*TSEQ + c*LC))*NST + n;
    float2 p = a;
    for (int j = 0; j < LC; ++j) {
        float2 add = cmul2(p, cin);
        float2 v = upk(base[(size_t)j*NST]);
        base[(size_t)j*NST] = pk(make_float2(v.x + add.x, v.y + add.y));
        p = cmul2(p, a);
    }
}

// ---------------- conv1: bf16 in, implicit-im2col MFMA (operand-swapped), bf16 out ----
__global__ __launch_bounds__(256, 4) void conv1_mfma(
    const bf16* __restrict__ X,
    const bf16* __restrict__ wB,    // [128][640]
    const float* __restrict__ bias,
    bf16* __restrict__ out,         // [B*Lout][128]
    int Tin, int Lout)
{
    __shared__ bf16 As[128][72];
    __shared__ bf16 Bs[128][72];
    int tid  = threadIdx.x;
    int lane = tid & 63;
    int wave = tid >> 6;
    int wm = wave >> 1, wn = wave & 1;
    int quad = lane >> 4, cl = lane & 15;
    int row0 = blockIdx.x * 128;
    int b  = row0 / Lout;
    int l0 = row0 % Lout;
    const bf16* Xb = X + (size_t)b*Tin*128;

    f32x4 acc[4][4] = {};

    for (int k0 = 0; k0 < 640; k0 += 64) {
        int tap = k0 / 128;
        int icb = k0 % 128;
        #pragma unroll
        for (int it = 0; it < 4; ++it) {
            int idx = it*256 + tid;
            int r = idx >> 3, kof = (idx & 7) * 8;
            int t = 2*(l0 + r) - 2 + tap;
            bf16x8 z = {0,0,0,0,0,0,0,0};
            if (t >= 0 && t < Tin) z = *(const bf16x8*)(Xb + (size_t)t*128 + icb + kof);
            *(bf16x8*)&As[r][kof] = z;
        }
        #pragma unroll
        for (int it = 0; it < 4; ++it) {
            int idx = it*256 + tid;
            int n = idx >> 3, kof = (idx & 7) * 8;
            *(bf16x8*)&Bs[n][kof] = *(const bf16x8*)(wB + (size_t)n*640 + k0 + kof);
        }
        __syncthreads();
        #pragma unroll
        for (int kk = 0; kk < 64; kk += 32) {
            bf16x8 af[4], bfr[4];
            #pragma unroll
            for (int i = 0; i < 4; ++i)
                af[i] = *(const bf16x8*)&As[wm*64 + i*16 + cl][kk + quad*8];
            #pragma unroll
            for (int j = 0; j < 4; ++j)
                bfr[j] = *(const bf16x8*)&Bs[wn*64 + j*16 + cl][kk + quad*8];
            #pragma unroll
            for (int i = 0; i < 4; ++i)
                #pragma unroll
                for (int j = 0; j < 4; ++j)
                    acc[i][j] = __builtin_amdgcn_mfma_f32_16x16x32_bf16(
                                    bfr[j], af[i], acc[i][j], 0, 0, 0);
        }
        __syncthreads();
    }

    #pragma unroll
    for (int i = 0; i < 4; ++i) {
        int grow = row0 + wm*64 + i*16 + cl;
        #pragma unroll
        for (int j = 0; j < 4; ++j) {
            int gcol = wn*64 + j*16 + quad*4;
            float4 bv = *(const float4*)(bias + gcol);
            float4 t;
            t.x = fmaxf(acc[i][j][0] + bv.x, 0.f); t.y = fmaxf(acc[i][j][1] + bv.y, 0.f);
            t.z = fmaxf(acc[i][j][2] + bv.z, 0.f); t.w = fmaxf(acc[i][j][3] + bv.w, 0.f);
            uint2 pu = make_uint2(pkpair(t.x, t.y), pkpair(t.z, t.w));
            *(uint2*)(out + (size_t)grow*128 + gcol) = pu;
        }
    }
}

// ---------------- conv2 (bf16 in) + fused relu + avg pool (operand-swapped) ----------
__global__ __launch_bounds__(256, 4) void conv2_pool(
    const bf16* __restrict__ X,     // [B][Tin][128]
    const bf16* __restrict__ wB,    // [128][640]
    const float* __restrict__ bias,
    float* __restrict__ outp,       // [B][128][64]
    int Tin, int Lout)
{
    __shared__ bf16 As[128][72];
    __shared__ bf16 Bs[128][72];
    int tid  = threadIdx.x;
    int lane = tid & 63;
    int wave = tid >> 6;
    int wm = wave >> 1, wn = wave & 1;
    int quad = lane >> 4, cl = lane & 15;
    int row0 = blockIdx.x * 128;
    int b  = row0 / Lout;
    int l0 = row0 % Lout;
    int d0 = l0 / 16;
    const bf16* Xb = X + (size_t)b*Tin*128;

    f32x4 acc[4][4] = {};

    for (int k0 = 0; k0 < 640; k0 += 64) {
        int tap = k0 / 128;
        int icb = k0 % 128;
        #pragma unroll
        for (int it = 0; it < 4; ++it) {
            int idx = it*256 + tid;
            int r = idx >> 3, kof = (idx & 7) * 8;
            int t = 2*(l0 + r) - 2 + tap;
            bf16x8 z = {0,0,0,0,0,0,0,0};
            if (t >= 0 && t < Tin) z = *(const bf16x8*)(Xb + (size_t)t*128 + icb + kof);
            *(bf16x8*)&As[r][kof] = z;
        }
        #pragma unroll
        for (int it = 0; it < 4; ++it) {
            int idx = it*256 + tid;
            int n = idx >> 3, kof = (idx & 7) * 8;
            *(bf16x8*)&Bs[n][kof] = *(const bf16x8*)(wB + (size_t)n*640 + k0 + kof);
        }
        __syncthreads();
        #pragma unroll
        for (int kk = 0; kk < 64; kk += 32) {
            bf16x8 af[4], bfr[4];
            #pragma unroll
            for (int i = 0; i < 4; ++i)
                af[i] = *(const bf16x8*)&As[wm*64 + i*16 + cl][kk + quad*8];
            #pragma unroll
            for (int j = 0; j < 4; ++j)
                bfr[j] = *(const bf16x8*)&Bs[wn*64 + j*16 + cl][kk + quad*8];
            #pragma unroll
            for (int i = 0; i < 4; ++i)
                #pragma unroll
                for (int j = 0; j < 4; ++j)
                    acc[i][j] = __builtin_amdgcn_mfma_f32_16x16x32_bf16(
                                    bfr[j], af[i], acc[i][j], 0, 0, 0);
        }
        __syncthreads();
    }

    #pragma unroll
    for (int j = 0; j < 4; ++j) {
        int gcol = wn*64 + j*16 + quad*4;
        float4 bv = *(const float4*)(bias + gcol);
        #pragma unroll
        for (int i = 0; i < 4; ++i) {
            float4 sp;
            sp.x = fmaxf(acc[i][j][0] + bv.x, 0.f);
            sp.y = fmaxf(acc[i][j][1] + bv.y, 0.f);
            sp.z = fmaxf(acc[i][j][2] + bv.z, 0.f);
            sp.w = fmaxf(acc[i][j][3] + bv.w, 0.f);
            #pragma unroll
            for (int off = 1; off <= 8; off <<= 1) {
                sp.x += __shfl_xor(sp.x, off);
                sp.y += __shfl_xor(sp.y, off);
                sp.z += __shfl_xor(sp.z, off);
                sp.w += __shfl_xor(sp.w, off);
            }
            if (cl == 0) {
                int d = d0 + wm*4 + i;
                float* op = outp + (size_t)b*8192 + (size_t)gcol*64 + d;
                op[0]   = sp.x * (1.f/16.f);
                op[64]  = sp.y * (1.f/16.f);
                op[128] = sp.z * (1.f/16.f);
                op[192] = sp.w * (1.f/16.f);
            }
        }
    }
}

extern "C" void kernel_launch(void* const* d_in, const int* in_sizes, int n_in,
                              void* d_out, int out_size, void* d_ws, size_t ws_size,
                              hipStream_t stream)
{
    (void)in_sizes; (void)n_in; (void)out_size; (void)ws_size;
    const float* x_in    = (const float*)d_in[0];
    const float* ln1_g   = (const float*)d_in[1];
    const float* ln1_b   = (const float*)d_in[2];
    const float* ln2_g   = (const float*)d_in[3];
    const float* ln2_b   = (const float*)d_in[4];
    const float* Lam_re  = (const float*)d_in[5];
    const float* Lam_im  = (const float*)d_in[6];
    const float* B_re    = (const float*)d_in[7];
    const float* B_im    = (const float*)d_in[8];
    const float* C_re    = (const float*)d_in[9];
    const float* C_im    = (const float*)d_in[10];
    const float* D_skip  = (const float*)d_in[11];
    const float* log_step= (const float*)d_in[12];
    const float* W1      = (const float*)d_in[13];
    const float* b1      = (const float*)d_in[14];
    const float* W2      = (const float*)d_in[15];
    const float* b2      = (const float*)d_in[16];
    const float* conv1_w = (const float*)d_in[17];
    const float* conv1_b = (const float*)d_in[18];
    const float* conv2_w = (const float*)d_in[19];
    const float* conv2_b = (const float*)d_in[20];
    float* out = (float*)d_out;

    // Workspace (~120 MB): Xbf bf16 32MB | Cbuf bf16 [BT,256] 64MB | Cv1 bf16 16MB
    //                      | munrs 1MB | params+carry ~3MB
    char* ws = (char*)d_ws;
    bf16*   Xbf    = (bf16*) (ws);
    bf16*   Cbuf   = (bf16*) (ws + (size_t)33554432);
    bf16*   Cv1    = (bf16*) (ws + (size_t)100663296);
    float2* munrs  = (float2*)(ws + (size_t)117440512);
    char*   wreg   = ws + (size_t)118489088;
    bf16*   Wbu_bf = (bf16*)(wreg);                  // 131072
    bf16*   Wc_bf  = (bf16*)(wreg + 131072);         // 131072
    bf16*   W1_bf  = (bf16*)(wreg + 262144);         // 131072
    bf16*   W2_bf  = (bf16*)(wreg + 393216);         // 131072
    float*  Sb     = (float*)(wreg + 524288);        // 2048
    float*  biasb  = (float*)(wreg + 526336);        // 2048
    float*  S1     = (float*)(wreg + 528384);        // 2048
    float*  bias1p = (float*)(wreg + 530432);        // 2048
    float*  gd     = (float*)(wreg + 532480);        // 1024
    float*  bd     = (float*)(wreg + 533504);        // 1024
    float4* coefs  = (float4*)(wreg + 534528);       // 4096
    bf16*   wB1    = (bf16*)(wreg + 538624);         // 163840
    bf16*   wB2    = (bf16*)(wreg + 702464);         // 163840
    float2* carry  = (float2*)(wreg + 866304);       // 2 MB

    prep_s5<<<2, 128, 0, stream>>>(Lam_re, Lam_im, B_re, B_im, C_re, C_im, log_step,
                                   ln1_g, ln1_b, D_skip,
                                   Wbu_bf, Wc_bf, Sb, biasb, gd, bd, coefs);
    prep_w1<<<2, 256, 0, stream>>>(W1, b1, ln2_g, ln2_b, W1_bf, S1, bias1p);
    prep_w2<<<2, 128, 0, stream>>>(W2, W2_bf);
    prep_wB<<<640, 256, 0, stream>>>(conv1_w, conv2_w, wB1, wB2);

    for (int i = 0; i < 2; ++i) {
        // ---- S5 sub-block: fused LN+Wbu (writes Bu + munrs), scan, Wc+resid+ud ----
        if (i == 0)
            lngemm<1, float><<<1024, 256, 0, stream>>>(
                x_in, Wbu_bf, Sb, biasb, Cbuf, munrs);
        else
            lngemm<1, bf16><<<1024, 256, 0, stream>>>(
                Xbf, Wbu_bf + 32768, Sb + 256, biasb + 256, Cbuf, munrs);
        scan_local<<<1024, 256, 0, stream>>>((unsigned int*)Cbuf, coefs + i*NST, carry);
        scan_carry<<<16, 256, 0, stream>>>(carry, coefs + i*NST);
        scan_fix<<<1024, 256, 0, stream>>>((unsigned int*)Cbuf, coefs + i*NST, carry);
        if (i == 0)
            gemm2<3, float><<<1024, 256, 0, stream>>>(
                Cbuf, Wc_bf, Xbf, nullptr, x_in, munrs, gd, bd);
        else
            gemm2<3, bf16><<<1024, 256, 0, stream>>>(
                Cbuf, Wc_bf + 32768, Xbf, nullptr, Xbf, munrs, gd + 128, bd + 128);
        // ---- MLP sub-block: fused LN+W1+gelu, W2+bias+resid ----
        lngemm<0, bf16><<<1024, 256, 0, stream>>>(
            Xbf, W1_bf + (size_t)i*32768, S1 + i*256, bias1p + i*256, Cbuf, nullptr);
        gemm2<2, bf16><<<1024, 256, 0, stream>>>(
            Cbuf, W2_bf + (size_t)i*32768, Xbf, b2 + i*HD, Xbf,
            nullptr, nullptr, nullptr);
    }

    // ---- head: conv1 (Xbf -> bf16) -> conv2+pool (-> d_out) ----
    conv1_mfma<<<512, 256, 0, stream>>>(Xbf, wB1, conv1_b, Cv1, 4096, 2048);
    conv2_pool<<<256, 256, 0, stream>>>(Cv1, wB2, conv2_b, out, 2048, 1024);
}

// Round 12
// 565.498 us; speedup vs baseline: 1.3844x; 1.3844x over previous
//
#include <hip/hip_runtime.h>
#include <math.h>

#define BATCH 32
#define TSEQ  4096
#define HD    128
#define NST   128
#define BT    (BATCH*TSEQ)     // 131072
#define LC    64               // scan chunk length
#define NCHK  (TSEQ/LC)        // 64 chunks

typedef unsigned short bf16;
typedef __attribute__((ext_vector_type(8))) short bf16x8;   // 8 bf16 = 4 VGPRs (MFMA A/B frag)
typedef __attribute__((ext_vector_type(4))) float f32x4;    // MFMA C/D frag

__device__ inline float bf2f(bf16 s) {
    union { unsigned int u; float f; } v; v.u = ((unsigned int)s) << 16; return v.f;
}
__device__ inline bf16 f2bf(float f) {
    union { float f; unsigned int u; } v; v.f = f;
    unsigned int u = v.u;
    unsigned int r = (u + 0x7fffu + ((u >> 16) & 1u)) >> 16;
    return (bf16)r;
}
// pack two f32 -> bf16 pair (round-half-up) in ~3 VALU via v_perm
__device__ inline unsigned int pkpair(float lo, float hi) {
    union { float f; unsigned int u; } a, b;
    a.f = lo; b.f = hi;
    return __builtin_amdgcn_perm(b.u + 0x8000u, a.u + 0x8000u, 0x07060302u);
}
__device__ inline bf16x8 pack8f(float4 f0, float4 f1) {
    union { bf16x8 v; unsigned int u[4]; } t;
    t.u[0] = pkpair(f0.x, f0.y);
    t.u[1] = pkpair(f0.z, f0.w);
    t.u[2] = pkpair(f1.x, f1.y);
    t.u[3] = pkpair(f1.z, f1.w);
    return t.v;
}
__device__ inline float2 cmul2(float2 a, float2 b) {
    return make_float2(a.x*b.x - a.y*b.y, a.x*b.y + a.y*b.x);
}
// tanh-form gelu: max |diff vs exact erf-gelu| ~1e-3, under bf16 noise here
__device__ inline float gelu_f(float x) {
    float u = x*(0.7978845608f + 0.0356774081f*x*x);
    return __fdividef(x, 1.f + __expf(-2.f*u));
}
__device__ inline float2 upk(unsigned int w) {     // bf16 pair -> fp32 pair
    union { unsigned int u; float f; } a, b;
    a.u = w << 16; b.u = w & 0xffff0000u;
    return make_float2(a.f, b.f);
}
__device__ inline unsigned int pk(float2 x) { return pkpair(x.x, x.y); }

// ---------------- S5 param prep: g-folded W'bu, S/bias, Wc, gd/bd, coefs, apow -------
__global__ void prep_s5(const float* __restrict__ Lam_re, const float* __restrict__ Lam_im,
                        const float* __restrict__ B_re,  const float* __restrict__ B_im,
                        const float* __restrict__ C_re,  const float* __restrict__ C_im,
                        const float* __restrict__ log_step,
                        const float* __restrict__ ln1_g, const float* __restrict__ ln1_b,
                        const float* __restrict__ D_skip,
                        bf16* __restrict__ Wbu_bf,  // [2][256][128], row 2n=Re 2n+1=Im, g-folded
                        bf16* __restrict__ Wc_bf,   // [2][128][256], col 2n=2Cre 2n+1=-2Cim
                        float* __restrict__ Sb, float* __restrict__ biasb,   // [2][256]
                        float* __restrict__ gd, float* __restrict__ bd,      // [2][128]
                        float4* __restrict__ coefs,
                        float2* __restrict__ apow)  // [2][64][128]: apow[i][j][n] = a^(j+1)
{
    int i = blockIdx.x, n = threadIdx.x;
    int in = i*NST + n;
    float lr = Lam_re[in], li = Lam_im[in];
    float dt = expf(log_step[in]);
    float ea = expf(lr*dt);
    float ar = ea*cosf(li*dt), ai = ea*sinf(li*dt);
    float xx = ar - 1.f, yy = ai;
    float den = lr*lr + li*li;
    float sr = (xx*lr + yy*li)/den;
    float si = (yy*lr - xx*li)/den;
    float2 a2 = make_float2(ar, ai);
    float2 p = a2;
    float2* apr = apow + (size_t)i*64*128;
    for (int j = 0; j < 64; ++j) {     // apow[j][n] = a^(j+1)
        apr[j*128 + n] = p;
        p = cmul2(p, a2);
    }
    // p is now a^65; recompute a^64 via repeated squaring for exactness
    float2 q = a2;
    #pragma unroll
    for (int t = 0; t < 6; ++t) q = cmul2(q, q);
    coefs[in] = make_float4(ar, ai, q.x, q.y);

    const float* g  = ln1_g + i*HD;
    const float* bb = ln1_b + i*HD;
    const float* br = B_re + (size_t)in*HD;
    const float* bi = B_im + (size_t)in*HD;
    bf16* wb = Wbu_bf + (size_t)i*256*128;
    float s_re = 0.f, s_im = 0.f, bc_re = 0.f, bc_im = 0.f;
    for (int h = 0; h < HD; ++h) {
        float wre = sr*br[h] - si*bi[h];
        float wim = sr*bi[h] + si*br[h];
        bf16 wrb = f2bf(g[h]*wre), wib = f2bf(g[h]*wim);
        wb[(2*n)*128 + h]   = wrb;
        wb[(2*n+1)*128 + h] = wib;
        s_re += bf2f(wrb); s_im += bf2f(wib);
        bc_re += bb[h]*wre; bc_im += bb[h]*wim;
    }
    Sb[i*256 + 2*n] = s_re;     Sb[i*256 + 2*n+1] = s_im;
    biasb[i*256 + 2*n] = bc_re; biasb[i*256 + 2*n+1] = bc_im;

    const float* cr = C_re + (size_t)i*HD*NST;
    const float* ci = C_im + (size_t)i*HD*NST;
    bf16* wc = Wc_bf + (size_t)i*128*256;
    for (int h = 0; h < HD; ++h) {
        wc[h*256 + 2*n]   = f2bf( 2.f * cr[h*NST + n]);
        wc[h*256 + 2*n+1] = f2bf(-2.f * ci[h*NST + n]);
    }
    gd[i*HD + n] = g[n]*D_skip[i*HD + n];
    bd[i*HD + n] = bb[n]*D_skip[i*HD + n];
}

// W1 -> g2-folded bf16 [f][h] + S1/bias1' (bias1' includes b1)
__global__ void prep_w1(const float* __restrict__ W1, const float* __restrict__ b1,
                        const float* __restrict__ ln2_g, const float* __restrict__ ln2_b,
                        bf16* __restrict__ W1_bf, float* __restrict__ S1,
                        float* __restrict__ bias1p)
{
    int i = blockIdx.x, f = threadIdx.x;       // f in [0,256)
    const float* g  = ln2_g + i*HD;
    const float* bb = ln2_b + i*HD;
    bf16* w = W1_bf + (size_t)i*256*128;
    float S = 0.f, bi_ = b1[i*256 + f];
    for (int h = 0; h < HD; ++h) {
        float wv = W1[(size_t)i*32768 + h*256 + f];
        bf16 wbv = f2bf(g[h]*wv);
        w[f*128 + h] = wbv;
        S += bf2f(wbv);
        bi_ += bb[h]*wv;
    }
    S1[i*256 + f] = S;
    bias1p[i*256 + f] = bi_;
}

// W2 -> plain bf16 transposed [h][f]
__global__ void prep_w2(const float* __restrict__ W2, bf16* __restrict__ W2_bf)
{
    int i = blockIdx.x, h = threadIdx.x;       // h in [0,128)
    bf16* w = W2_bf + (size_t)i*128*256;
    for (int f = 0; f < 256; ++f)
        w[h*256 + f] = f2bf(W2[(size_t)i*32768 + f*128 + h]);
}

// conv weights [c][ic][tap] -> bf16 [c][tap*128+ic]
__global__ void prep_wB(const float* __restrict__ w1, const float* __restrict__ w2,
                        bf16* __restrict__ wB1, bf16* __restrict__ wB2)
{
    int idx = blockIdx.x*256 + threadIdx.x;
    if (idx >= 163840) return;
    const float* w = (idx < 81920) ? w1 : w2;
    bf16* wb       = (idx < 81920) ? wB1 : wB2;
    int r   = idx % 81920;
    int c   = r / 640;
    int tap = (r % 640) / 128;
    int ic  = r % 128;
    wb[r] = f2bf(w[(c*128 + ic)*5 + tap]);
}

// ---------------- fused LN + GEMM (K=128, N=256), bf16 out, persistent waves ----------
// Operand-swapped MFMA: lane cl owns output row t = s*16+cl directly.
// UD=1: stores per-row (mu,rs) to munrs (ud recomputed downstream in gemm2). UD=0: gelu.
template<int UD, typename TA>
__global__ __launch_bounds__(1024, 4) void lngemm(
    const TA* __restrict__ A,          // [BT,128] fp32 or bf16
    const bf16* __restrict__ Bt,       // [256][128] g-folded
    const float* __restrict__ Svec, const float* __restrict__ bvec,  // [256]
    bf16* __restrict__ outB,           // [BT,256]
    float2* __restrict__ munrs)        // [BT], UD=1 only
{
    __shared__ bf16 Bs[256*136];       // 69632 B (+8 pad per row)
    __shared__ float Sl[256], bl[256];

    int tid = threadIdx.x;
    #pragma unroll
    for (int it = 0; it < 4; ++it) {
        int f = it*1024 + tid;
        int n = f >> 4, kk = (f & 15)*8;
        *(bf16x8*)&Bs[n*136 + kk] = *(const bf16x8*)(Bt + n*128 + kk);
    }
    if (tid < 256) { Sl[tid] = Svec[tid]; bl[tid] = bvec[tid]; }
    __syncthreads();

    int wid = tid >> 6, lane = tid & 63;
    int quad = lane >> 4, cl = lane & 15;
    int s = blockIdx.x*16 + wid;                  // strip [0,8192)
    size_t row = (size_t)s*16 + cl;

    // streaming load: stats + bf16 frags (no fp32 row kept live)
    bf16x8 af[4];
    float sm = 0.f, sq = 0.f;
    if constexpr (sizeof(TA) == 2) {
        const bf16* ar = (const bf16*)A + row*128;
        #pragma unroll
        for (int ks = 0; ks < 4; ++ks) {
            af[ks] = *(const bf16x8*)(ar + quad*8 + ks*32);
            union { bf16x8 v; unsigned int u[4]; } aa; aa.v = af[ks];
            #pragma unroll
            for (int jp = 0; jp < 4; ++jp) {
                float2 vv = upk(aa.u[jp]);
                sm += vv.x + vv.y;
                sq += vv.x*vv.x + vv.y*vv.y;
            }
        }
    } else {
        const float* ar = (const float*)A + row*128;
        #pragma unroll
        for (int ks = 0; ks < 4; ++ks) {
            float4 f0 = *(const float4*)(ar + quad*8 + ks*32);
            float4 f1 = *(const float4*)(ar + quad*8 + ks*32 + 4);
            sm += f0.x + f0.y + f0.z + f0.w + f1.x + f1.y + f1.z + f1.w;
            sq += f0.x*f0.x + f0.y*f0.y + f0.z*f0.z + f0.w*f0.w
                + f1.x*f1.x + f1.y*f1.y + f1.z*f1.z + f1.w*f1.w;
            af[ks] = pack8f(f0, f1);
        }
    }
    // full-row stats via cross-quad reduce (4 quads of same cl share a row)
    sm += __shfl_xor(sm, 16); sm += __shfl_xor(sm, 32);
    sq += __shfl_xor(sq, 16); sq += __shfl_xor(sq, 32);
    float mu = sm * (1.f/128.f);
    float rs = rsqrtf(sq*(1.f/128.f) - mu*mu + 1e-5f);
    float mr = mu*rs;

    if constexpr (UD) {
        if (quad == 0) munrs[row] = make_float2(mu, rs);
    }

    #pragma unroll
    for (int half = 0; half < 2; ++half) {
        f32x4 acc[8] = {};
        #pragma unroll
        for (int nt = 0; nt < 8; ++nt) {
            const bf16* wrp = &Bs[((half*8+nt)*16 + cl)*136 + quad*8];
            #pragma unroll
            for (int ks = 0; ks < 4; ++ks)
                acc[nt] = __builtin_amdgcn_mfma_f32_16x16x32_bf16(
                              *(const bf16x8*)(wrp + ks*32), af[ks], acc[nt], 0, 0, 0);
        }
        // D: col=cl -> t=row, rows quad*4+r -> n within 16-group. Direct store.
        #pragma unroll
        for (int nt = 0; nt < 8; ++nt) {
            int n0 = (half*8+nt)*16 + quad*4;
            float4 S4 = *(const float4*)&Sl[n0];
            float4 b4 = *(const float4*)&bl[n0];
            float4 o;
            o.x = rs*acc[nt][0] - mr*S4.x + b4.x;
            o.y = rs*acc[nt][1] - mr*S4.y + b4.y;
            o.z = rs*acc[nt][2] - mr*S4.z + b4.z;
            o.w = rs*acc[nt][3] - mr*S4.w + b4.w;
            if constexpr (!UD) {
                o.x = gelu_f(o.x); o.y = gelu_f(o.y);
                o.z = gelu_f(o.z); o.w = gelu_f(o.w);
            }
            uint2 pu = make_uint2(pkpair(o.x, o.y), pkpair(o.z, o.w));
            *(uint2*)(outB + row*256 + n0) = pu;
        }
    }
}

// ---------------- GEMM K=256 N=128 (bf16 A), bf16 out, persistent waves --------------
// Operand-swapped; lane cl owns output row t directly.
// EPI=2: out = acc + bias + resid.
// EPI=3: A-load applies the scan fix on-the-fly (xs += a^{j+1}*carry_in), then
//        out = resid + acc + (resid-mu)*rs*gd + bd.
template<int EPI, typename TR>
__global__ __launch_bounds__(1024, 4) void gemm2(
    const bf16* __restrict__ A,        // [BT,256]
    const bf16* __restrict__ Bt,       // [128][256]
    bf16* out,                         // [BT,128] (may alias resid, same-elem r-then-w)
    const float* __restrict__ bias,    // EPI=2
    const TR* resid,                   // [BT,128]
    const float2* __restrict__ munrs,  // EPI=3
    const float* __restrict__ gdp, const float* __restrict__ bdp,   // EPI=3
    const float2* __restrict__ carry,  // EPI=3: [NCHK][B][128] exclusive chunk prefix
    const float2* __restrict__ apow)   // EPI=3: [64][128] a^(j+1)
{
    __shared__ bf16 Bs[128*264];       // 67584 B
    __shared__ float gdl[128], bdl[128];

    int tid = threadIdx.x;
    #pragma unroll
    for (int it = 0; it < 4; ++it) {
        int f = it*1024 + tid;
        int n = f >> 5, kk = (f & 31)*8;
        *(bf16x8*)&Bs[n*264 + kk] = *(const bf16x8*)(Bt + n*256 + kk);
    }
    if constexpr (EPI == 3) {
        if (tid < 128) { gdl[tid] = gdp[tid]; bdl[tid] = bdp[tid]; }
    } else {
        if (tid < 128) { gdl[tid] = bias[tid]; }
    }
    __syncthreads();

    int wid = tid >> 6, lane = tid & 63;
    int quad = lane >> 4, cl = lane & 15;
    int s = blockIdx.x*16 + wid;
    size_t row = (size_t)s*16 + cl;

    float mu = 0.f, rs = 0.f;
    if constexpr (EPI == 3) { float2 m2 = munrs[row]; mu = m2.x; rs = m2.y; }

    bf16x8 af[8];
    const bf16* ar = A + row*256 + quad*8;
    if constexpr (EPI == 3) {
        // scan fix-up fused into the A-load
        int b  = (int)(row >> 12);             // row / 4096
        int tp = (int)(row & 4095);
        int cc = tp >> 6, j = tp & 63;
        const float2* cin = carry + (size_t)cc*(BATCH*NST) + (size_t)b*NST;
        const float2* ap  = apow + (size_t)j*128;
        #pragma unroll
        for (int ks = 0; ks < 8; ++ks) {
            union { bf16x8 v; unsigned int u[4]; } t;
            t.v = *(const bf16x8*)(ar + ks*32);
            int n0 = quad*4 + ks*16;           // complex index of t.u[0]
            #pragma unroll
            for (int jp = 0; jp < 4; ++jp) {
                float2 v  = upk(t.u[jp]);
                float2 ad = cmul2(ap[n0+jp], cin[n0+jp]);
                t.u[jp] = pk(make_float2(v.x + ad.x, v.y + ad.y));
            }
            af[ks] = t.v;
        }
    } else {
        #pragma unroll
        for (int ks = 0; ks < 8; ++ks)
            af[ks] = *(const bf16x8*)(ar + ks*32);
    }

    f32x4 acc[8] = {};
    #pragma unroll
    for (int nt = 0; nt < 8; ++nt) {
        const bf16* wrp = &Bs[(nt*16 + cl)*264 + quad*8];
        #pragma unroll
        for (int ks = 0; ks < 8; ++ks)
            acc[nt] = __builtin_amdgcn_mfma_f32_16x16x32_bf16(
                          *(const bf16x8*)(wrp + ks*32), af[ks], acc[nt], 0, 0, 0);
    }

    #pragma unroll
    for (int nt = 0; nt < 8; ++nt) {
        int n0 = nt*16 + quad*4;
        size_t oidx = row*128 + n0;
        float4 rv;
        if constexpr (sizeof(TR) == 2) {
            ushort4 u4 = *(const ushort4*)((const bf16*)resid + oidx);
            rv = make_float4(bf2f(u4.x), bf2f(u4.y), bf2f(u4.z), bf2f(u4.w));
        } else {
            rv = *(const float4*)((const float*)resid + oidx);
        }
        float4 o;
        if constexpr (EPI == 2) {
            float4 bv = *(const float4*)&gdl[n0];
            o.x = acc[nt][0] + bv.x + rv.x; o.y = acc[nt][1] + bv.y + rv.y;
            o.z = acc[nt][2] + bv.z + rv.z; o.w = acc[nt][3] + bv.w + rv.w;
        } else {
            float4 g4 = *(const float4*)&gdl[n0];
            float4 b4 = *(const float4*)&bdl[n0];
            o.x = rv.x + acc[nt][0] + (rv.x - mu)*rs*g4.x + b4.x;
            o.y = rv.y + acc[nt][1] + (rv.y - mu)*rs*g4.y + b4.y;
            o.z = rv.z + acc[nt][2] + (rv.z - mu)*rs*g4.z + b4.z;
            o.w = rv.w + acc[nt][3] + (rv.w - mu)*rs*g4.w + b4.w;
        }
        uint2 pu = make_uint2(pkpair(o.x, o.y), pkpair(o.z, o.w));
        *(uint2*)(out + oidx) = pu;
    }
}

// ---------------- chunked scan on bf16-pair xs: x_t = a*x_{t-1} + Bu_t ---------------
// Local pass only; cross-chunk fix is fused into gemm2<3>.
__global__ __launch_bounds__(256) void scan_local(unsigned int* __restrict__ xs,
                                                  const float4* __restrict__ coefs,
                                                  float2* __restrict__ carry)
{
    int flat = blockIdx.x*256 + threadIdx.x;  // 2^18
    int n = flat & 127;
    int b = (flat >> 7) & 31;
    int c = flat >> 12;
    float4 cf = coefs[n];
    float2 a = make_float2(cf.x, cf.y);
    unsigned int* base = xs + ((size_t)(b*TSEQ + c*LC))*NST + n;
    float2 x = make_float2(0.f, 0.f);
    for (int j = 0; j < LC; ++j) {
        float2 v = upk(base[(size_t)j*NST]);
        x = make_float2(a.x*x.x - a.y*x.y + v.x, a.x*x.y + a.y*x.x + v.y);
        base[(size_t)j*NST] = pk(x);
    }
    carry[c*(BATCH*NST) + b*NST + n] = x;
}

__global__ void scan_carry(float2* __restrict__ carry, const float4* __restrict__ coefs)
{
    int flat = blockIdx.x*256 + threadIdx.x;  // 4096 = B*N
    int n = flat & 127;
    float4 cf = coefs[n];
    float2 aL = make_float2(cf.z, cf.w);
    float2 x = make_float2(0.f, 0.f);
    for (int c = 0; c < NCHK; ++c) {
        float2* p = carry + c*(BATCH*NST) + flat;
        float2 v = *p;
        *p = x;                                // exclusive prefix
        x = make_float2(aL.x*x.x - aL.y*x.y + v.x, aL.x*x.y + aL.y*x.x + v.y);
    }
}

// ---------------- conv1: bf16 in, implicit-im2col MFMA (operand-swapped), bf16 out ----
__global__ __launch_bounds__(256, 4) void conv1_mfma(
    const bf16* __restrict__ X,
    const bf16* __restrict__ wB,    // [128][640]
    const float* __restrict__ bias,
    bf16* __restrict__ out,         // [B*Lout][128]
    int Tin, int Lout)
{
    __shared__ bf16 As[128][72];
    __shared__ bf16 Bs[128][72];
    int tid  = threadIdx.x;
    int lane = tid & 63;
    int wave = tid >> 6;
    int wm = wave >> 1, wn = wave & 1;
    int quad = lane >> 4, cl = lane & 15;
    int row0 = blockIdx.x * 128;
    int b  = row0 / Lout;
    int l0 = row0 % Lout;
    const bf16* Xb = X + (size_t)b*Tin*128;

    f32x4 acc[4][4] = {};

    for (int k0 = 0; k0 < 640; k0 += 64) {
        int tap = k0 / 128;
        int icb = k0 % 128;
        #pragma unroll
        for (int it = 0; it < 4; ++it) {
            int idx = it*256 + tid;
            int r = idx >> 3, kof = (idx & 7) * 8;
            int t = 2*(l0 + r) - 2 + tap;
            bf16x8 z = {0,0,0,0,0,0,0,0};
            if (t >= 0 && t < Tin) z = *(const bf16x8*)(Xb + (size_t)t*128 + icb + kof);
            *(bf16x8*)&As[r][kof] = z;
        }
        #pragma unroll
        for (int it = 0; it < 4; ++it) {
            int idx = it*256 + tid;
            int n = idx >> 3, kof = (idx & 7) * 8;
            *(bf16x8*)&Bs[n][kof] = *(const bf16x8*)(wB + (size_t)n*640 + k0 + kof);
        }
        __syncthreads();
        #pragma unroll
        for (int kk = 0; kk < 64; kk += 32) {
            bf16x8 af[4], bfr[4];
            #pragma unroll
            for (int i = 0; i < 4; ++i)
                af[i] = *(const bf16x8*)&As[wm*64 + i*16 + cl][kk + quad*8];
            #pragma unroll
            for (int j = 0; j < 4; ++j)
                bfr[j] = *(const bf16x8*)&Bs[wn*64 + j*16 + cl][kk + quad*8];
            #pragma unroll
            for (int i = 0; i < 4; ++i)
                #pragma unroll
                for (int j = 0; j < 4; ++j)
                    acc[i][j] = __builtin_amdgcn_mfma_f32_16x16x32_bf16(
                                    bfr[j], af[i], acc[i][j], 0, 0, 0);
        }
        __syncthreads();
    }

    #pragma unroll
    for (int i = 0; i < 4; ++i) {
        int grow = row0 + wm*64 + i*16 + cl;
        #pragma unroll
        for (int j = 0; j < 4; ++j) {
            int gcol = wn*64 + j*16 + quad*4;
            float4 bv = *(const float4*)(bias + gcol);
            float4 t;
            t.x = fmaxf(acc[i][j][0] + bv.x, 0.f); t.y = fmaxf(acc[i][j][1] + bv.y, 0.f);
            t.z = fmaxf(acc[i][j][2] + bv.z, 0.f); t.w = fmaxf(acc[i][j][3] + bv.w, 0.f);
            uint2 pu = make_uint2(pkpair(t.x, t.y), pkpair(t.z, t.w));
            *(uint2*)(out + (size_t)grow*128 + gcol) = pu;
        }
    }
}

// ---------------- conv2 (bf16 in) + fused relu + avg pool (operand-swapped) ----------
__global__ __launch_bounds__(256, 4) void conv2_pool(
    const bf16* __restrict__ X,     // [B][Tin][128]
    const bf16* __restrict__ wB,    // [128][640]
    const float* __restrict__ bias,
    float* __restrict__ outp,       // [B][128][64]
    int Tin, int Lout)
{
    __shared__ bf16 As[128][72];
    __shared__ bf16 Bs[128][72];
    int tid  = threadIdx.x;
    int lane = tid & 63;
    int wave = tid >> 6;
    int wm = wave >> 1, wn = wave & 1;
    int quad = lane >> 4, cl = lane & 15;
    int row0 = blockIdx.x * 128;
    int b  = row0 / Lout;
    int l0 = row0 % Lout;
    int d0 = l0 / 16;
    const bf16* Xb = X + (size_t)b*Tin*128;

    f32x4 acc[4][4] = {};

    for (int k0 = 0; k0 < 640; k0 += 64) {
        int tap = k0 / 128;
        int icb = k0 % 128;
        #pragma unroll
        for (int it = 0; it < 4; ++it) {
            int idx = it*256 + tid;
            int r = idx >> 3, kof = (idx & 7) * 8;
            int t = 2*(l0 + r) - 2 + tap;
            bf16x8 z = {0,0,0,0,0,0,0,0};
            if (t >= 0 && t < Tin) z = *(const bf16x8*)(Xb + (size_t)t*128 + icb + kof);
            *(bf16x8*)&As[r][kof] = z;
        }
        #pragma unroll
        for (int it = 0; it < 4; ++it) {
            int idx = it*256 + tid;
            int n = idx >> 3, kof = (idx & 7) * 8;
            *(bf16x8*)&Bs[n][kof] = *(const bf16x8*)(wB + (size_t)n*640 + k0 + kof);
        }
        __syncthreads();
        #pragma unroll
        for (int kk = 0; kk < 64; kk += 32) {
            bf16x8 af[4], bfr[4];
            #pragma unroll
            for (int i = 0; i < 4; ++i)
                af[i] = *(const bf16x8*)&As[wm*64 + i*16 + cl][kk + quad*8];
            #pragma unroll
            for (int j = 0; j < 4; ++j)
                bfr[j] = *(const bf16x8*)&Bs[wn*64 + j*16 + cl][kk + quad*8];
            #pragma unroll
            for (int i = 0; i < 4; ++i)
                #pragma unroll
                for (int j = 0; j < 4; ++j)
                    acc[i][j] = __builtin_amdgcn_mfma_f32_16x16x32_bf16(
                                    bfr[j], af[i], acc[i][j], 0, 0, 0);
        }
        __syncthreads();
    }

    #pragma unroll
    for (int j = 0; j < 4; ++j) {
        int gcol = wn*64 + j*16 + quad*4;
        float4 bv = *(const float4*)(bias + gcol);
        #pragma unroll
        for (int i = 0; i < 4; ++i) {
            float4 sp;
            sp.x = fmaxf(acc[i][j][0] + bv.x, 0.f);
            sp.y = fmaxf(acc[i][j][1] + bv.y, 0.f);
            sp.z = fmaxf(acc[i][j][2] + bv.z, 0.f);
            sp.w = fmaxf(acc[i][j][3] + bv.w, 0.f);
            #pragma unroll
            for (int off = 1; off <= 8; off <<= 1) {
                sp.x += __shfl_xor(sp.x, off);
                sp.y += __shfl_xor(sp.y, off);
                sp.z += __shfl_xor(sp.z, off);
                sp.w += __shfl_xor(sp.w, off);
            }
            if (cl == 0) {
                int d = d0 + wm*4 + i;
                float* op = outp + (size_t)b*8192 + (size_t)gcol*64 + d;
                op[0]   = sp.x * (1.f/16.f);
                op[64]  = sp.y * (1.f/16.f);
                op[128] = sp.z * (1.f/16.f);
                op[192] = sp.w * (1.f/16.f);
            }
        }
    }
}

extern "C" void kernel_launch(void* const* d_in, const int* in_sizes, int n_in,
                              void* d_out, int out_size, void* d_ws, size_t ws_size,
                              hipStream_t stream)
{
    (void)in_sizes; (void)n_in; (void)out_size; (void)ws_size;
    const float* x_in    = (const float*)d_in[0];
    const float* ln1_g   = (const float*)d_in[1];
    const float* ln1_b   = (const float*)d_in[2];
    const float* ln2_g   = (const float*)d_in[3];
    const float* ln2_b   = (const float*)d_in[4];
    const float* Lam_re  = (const float*)d_in[5];
    const float* Lam_im  = (const float*)d_in[6];
    const float* B_re    = (const float*)d_in[7];
    const float* B_im    = (const float*)d_in[8];
    const float* C_re    = (const float*)d_in[9];
    const float* C_im    = (const float*)d_in[10];
    const float* D_skip  = (const float*)d_in[11];
    const float* log_step= (const float*)d_in[12];
    const float* W1      = (const float*)d_in[13];
    const float* b1      = (const float*)d_in[14];
    const float* W2      = (const float*)d_in[15];
    const float* b2      = (const float*)d_in[16];
    const float* conv1_w = (const float*)d_in[17];
    const float* conv1_b = (const float*)d_in[18];
    const float* conv2_w = (const float*)d_in[19];
    const float* conv2_b = (const float*)d_in[20];
    float* out = (float*)d_out;

    // Workspace (~122 MB): Xbf bf16 32MB | Cbuf bf16 [BT,256] 64MB | Cv1 bf16 16MB
    //                      | munrs 1MB | params+carry+apow ~4MB
    char* ws = (char*)d_ws;
    bf16*   Xbf    = (bf16*) (ws);
    bf16*   Cbuf   = (bf16*) (ws + (size_t)33554432);
    bf16*   Cv1    = (bf16*) (ws + (size_t)100663296);
    float2* munrs  = (float2*)(ws + (size_t)117440512);
    char*   wreg   = ws + (size_t)118489088;
    bf16*   Wbu_bf = (bf16*)(wreg);                  // 131072
    bf16*   Wc_bf  = (bf16*)(wreg + 131072);         // 131072
    bf16*   W1_bf  = (bf16*)(wreg + 262144);         // 131072
    bf16*   W2_bf  = (bf16*)(wreg + 393216);         // 131072
    float*  Sb     = (float*)(wreg + 524288);        // 2048
    float*  biasb  = (float*)(wreg + 526336);        // 2048
    float*  S1     = (float*)(wreg + 528384);        // 2048
    float*  bias1p = (float*)(wreg + 530432);        // 2048
    float*  gd     = (float*)(wreg + 532480);        // 1024
    float*  bd     = (float*)(wreg + 533504);        // 1024
    float4* coefs  = (float4*)(wreg + 534528);       // 4096
    bf16*   wB1    = (bf16*)(wreg + 538624);         // 163840
    bf16*   wB2    = (bf16*)(wreg + 702464);         // 163840
    float2* carry  = (float2*)(wreg + 866304);       // 2 MB
    float2* apow   = (float2*)(wreg + 2963456);      // 2*64*128*8 = 131072

    prep_s5<<<2, 128, 0, stream>>>(Lam_re, Lam_im, B_re, B_im, C_re, C_im, log_step,
                                   ln1_g, ln1_b, D_skip,
                                   Wbu_bf, Wc_bf, Sb, biasb, gd, bd, coefs, apow);
    prep_w1<<<2, 256, 0, stream>>>(W1, b1, ln2_g, ln2_b, W1_bf, S1, bias1p);
    prep_w2<<<2, 128, 0, stream>>>(W2, W2_bf);
    prep_wB<<<640, 256, 0, stream>>>(conv1_w, conv2_w, wB1, wB2);

    for (int i = 0; i < 2; ++i) {
        // ---- S5 sub-block: LN+Wbu (Bu + munrs), local scan + carry, Wc+fix+resid+ud ----
        if (i == 0)
            lngemm<1, float><<<512, 1024, 0, stream>>>(
                x_in, Wbu_bf, Sb, biasb, Cbuf, munrs);
        else
            lngemm<1, bf16><<<512, 1024, 0, stream>>>(
                Xbf, Wbu_bf + 32768, Sb + 256, biasb + 256, Cbuf, munrs);
        scan_local<<<1024, 256, 0, stream>>>((unsigned int*)Cbuf, coefs + i*NST, carry);
        scan_carry<<<16, 256, 0, stream>>>(carry, coefs + i*NST);
        if (i == 0)
            gemm2<3, float><<<512, 1024, 0, stream>>>(
                Cbuf, Wc_bf, Xbf, nullptr, x_in, munrs, gd, bd,
                carry, apow);
        else
            gemm2<3, bf16><<<512, 1024, 0, stream>>>(
                Cbuf, Wc_bf + 32768, Xbf, nullptr, Xbf, munrs, gd + 128, bd + 128,
                carry, apow + 64*128);
        // ---- MLP sub-block: fused LN+W1+gelu, W2+bias+resid ----
        lngemm<0, bf16><<<512, 1024, 0, stream>>>(
            Xbf, W1_bf + (size_t)i*32768, S1 + i*256, bias1p + i*256, Cbuf, nullptr);
        gemm2<2, bf16><<<512, 1024, 0, stream>>>(
            Cbuf, W2_bf + (size_t)i*32768, Xbf, b2 + i*HD, Xbf,
            nullptr, nullptr, nullptr, nullptr, nullptr);
    }

    // ---- head: conv1 (Xbf -> bf16) -> conv2+pool (-> d_out) ----
    conv1_mfma<<<512, 256, 0, stream>>>(Xbf, wB1, conv1_b, Cv1, 4096, 2048);
    conv2_pool<<<256, 256, 0, stream>>>(Cv1, wB2, conv2_b, out, 2048, 1024);
}